// Round 4
// baseline (85.669 us; speedup 1.0000x reference)
//
#include <hip/hip_runtime.h>

// Conv4D (2,8,7,7,48,48) fp32, 3x3x3x3 pad 1, 8->8 ch — bf16 MFMA implicit GEMM.
// R4: LDS-staged x tiles (kills the 243 MB L2/L3 B-gather), block = 6-row strip.
//
// d_ws layout (re-poisoned each launch; fully rewritten by prep):
//   [0,       3920000)  xp: bf16 x as [b][uv 49][hh 50][ww 50][c 8], h/w halo zeros
//   [3920000, 3940992)  Wp: A-frag weights [tap 82][m 16][j 8] bf16 (tap 81 = 0)

typedef __attribute__((ext_vector_type(8))) short short8;
typedef __attribute__((ext_vector_type(4))) float f32x4;
typedef __attribute__((ext_vector_type(4))) int   i32x4;

#define CSTRIDE (49 * 2304)
#define WP_OFF  3920000

__device__ __forceinline__ unsigned short f2bf(float f) {
    union { float f; unsigned u; } v; v.f = f;
    unsigned u = v.u;
    return (unsigned short)((u + 0x7FFF + ((u >> 16) & 1)) >> 16);  // RNE
}

// prep: g < 245000 -> xp group (8 ch), else Wp element (10496 = 82*128).
__global__ __launch_bounds__(256)
void prep(const float* __restrict__ x, const float* __restrict__ conv,
          unsigned short* __restrict__ ws16) {
    int g = blockIdx.x * 256 + threadIdx.x;
    if (g < 245000) {
        unsigned short vals[8];
#pragma unroll
        for (int c = 0; c < 8; ++c) vals[c] = 0;
        int b  = g / 122500;
        int r  = g - b * 122500;
        int uv = r / 2500;
        int p  = r - uv * 2500;
        int hh = p / 50, ww = p - hh * 50;
        int h = hh - 1, w = ww - 1;
        if (((unsigned)h < 48u) && ((unsigned)w < 48u)) {
            const float* xb = x + ((size_t)b * 8 * 49 + uv) * 2304 + h * 48 + w;
#pragma unroll
            for (int c = 0; c < 8; ++c) vals[c] = f2bf(xb[(size_t)c * CSTRIDE]);
        }
        *(short8*)(ws16 + (size_t)g * 8) = *(const short8*)vals;
    } else {
        int i = g - 245000;
        if (i < 10496) {                      // Wp[tap][m][j]
            int tap = i >> 7;
            int r   = i & 127;
            int m   = r >> 3, j = r & 7;
            unsigned short v = 0;
            if (tap < 81 && m < 8) v = f2bf(conv[m * 648 + tap * 8 + j]);
            ws16[WP_OFF / 2 + i] = v;
        }
    }
}

// Main: grid (8 row-strips, 98 images), 384 threads = 6 waves; wave = output row.
__global__ __launch_bounds__(384, 3)
void conv4d_mfma(const unsigned short* __restrict__ ws16,
                 const float* __restrict__ bias,
                 float* __restrict__ out) {
    __shared__ unsigned short xtile[9 * 8 * 50 * 8];  // [slice 9][row 8][col 50][c 8], 57.6 KB
    __shared__ int taboff_s[88];                      // slot -> xtile byte offset (block part)
    __shared__ int woff_s[88];                        // slot -> Wp byte offset
    __shared__ int s_vt[9];
    __shared__ int s_nv;

    const int img = blockIdx.y;              // b*49 + uv
    const int rt  = blockIdx.x;              // row strip
    const int r0  = rt * 6;
    const int b   = img / 49;
    const int uvr = img - b * 49;
    const int u   = uvr / 7;
    const int v   = uvr - u * 7;

    if (threadIdx.x == 0) {
        int nv = 0;
        for (int i01 = 0; i01 < 9; ++i01) {
            int i0 = i01 / 3, i1 = i01 - 3 * i0;
            int uu = u + i0 - 1, vv = v + i1 - 1;
            if (((unsigned)uu < 7u) && ((unsigned)vv < 7u)) s_vt[nv++] = i01;
        }
        s_nv = nv;
    }

    // Stage 9 slices x 8 rows x 50 cols (16 B groups) global->LDS; invalid slice -> 0.
    {
        const char* xpb = (const char*)ws16;
        const i32x4 z = (i32x4){0, 0, 0, 0};
        for (int i = threadIdx.x; i < 3600; i += 384) {
            int sl = i / 400;                // slice (i01)
            int k  = i - sl * 400;           // 16B chunk within 8x50 rows
            int i0 = sl / 3, i1 = sl - 3 * i0;
            int uu = u + i0 - 1, vv = v + i1 - 1;
            bool valid = ((unsigned)uu < 7u) && ((unsigned)vv < 7u);
            i32x4 val = z;
            if (valid) {
                const char* src = xpb + (size_t)b * 1960000 +
                                  (uu * 7 + vv) * 40000 + (r0 * 50 + k) * 16;
                val = *(const i32x4*)src;
            }
            *(i32x4*)((char*)xtile + i * 16) = val;
        }
    }
    __syncthreads();

    const int nv     = s_nv;
    const int nchunk = (nv * 9 + 3) >> 2;

    if (threadIdx.x < 88) {
        int s = threadIdx.x;
        if (s < nv * 9) {
            int g9  = s / 9, hw9 = s - 9 * g9;
            int i01 = s_vt[g9];
            int i2 = hw9 / 3, i3 = hw9 - 3 * i2;
            taboff_s[s] = ((i01 * 8 + i2) * 50 + i3) * 16;
            woff_s[s]   = (i01 * 9 + hw9) * 256;
        } else {
            taboff_s[s] = 0;                 // read anything; weights are zero
            woff_s[s]   = 81 * 256;          // tap 81 = zeros
        }
    }
    __syncthreads();

    const int lane = threadIdx.x & 63;
    const int wave = threadIdx.x >> 6;       // output row within strip (0..5)
    const int n    = lane & 15;              // spatial col within 16-tile
    const int quad = lane >> 4;              // tap-slot within chunk
    const int myoff = (wave * 50 + n) * 16;  // per-lane xtile byte offset

    const char* wpb = (const char*)ws16 + WP_OFF;
    const char* xt  = (const char*)xtile;

    f32x4 acc0 = (f32x4){0.f, 0.f, 0.f, 0.f};
    f32x4 acc1 = acc0, acc2 = acc0;

    // Manual 1-ahead weight prefetch (tables padded to 88 -> branchless).
    short8 wf = *(const short8*)(wpb + woff_s[quad] + n * 16);
    for (int c = 0; c < nchunk; ++c) {
        int nslot = 4 * (c + 1) + quad;
        short8 wfn = *(const short8*)(wpb + woff_s[nslot] + n * 16);
        const char* base = xt + taboff_s[4 * c + quad] + myoff;
        short8 xf0 = *(const short8*)(base);
        short8 xf1 = *(const short8*)(base + 256);
        short8 xf2 = *(const short8*)(base + 512);
        acc0 = __builtin_amdgcn_mfma_f32_16x16x32_bf16(wf, xf0, acc0, 0, 0, 0);
        acc1 = __builtin_amdgcn_mfma_f32_16x16x32_bf16(wf, xf1, acc1, 0, 0, 0);
        acc2 = __builtin_amdgcn_mfma_f32_16x16x32_bf16(wf, xf2, acc2, 0, 0, 0);
        wf = wfn;
    }

    // C/D: row(=o) = quad*4 + reg, col(=spatial w) = lane&15. Rows 8..15 unused.
    if (quad < 2) {
        f32x4 bb = *(const f32x4*)(bias + quad * 4);
        const int h = r0 + wave;
        float* ob = out + ((size_t)b * 8 * 49 + uvr) * 2304 + h * 48 + n;
        f32x4 av[3] = {acc0, acc1, acc2};
#pragma unroll
        for (int t = 0; t < 3; ++t) {
#pragma unroll
            for (int r = 0; r < 4; ++r) {
                int o = quad * 4 + r;
                ob[(size_t)o * CSTRIDE + t * 16] = av[t][r] + bb[r];
            }
        }
    }
}

extern "C" void kernel_launch(void* const* d_in, const int* in_sizes, int n_in,
                              void* d_out, int out_size, void* d_ws, size_t ws_size,
                              hipStream_t stream) {
    const float* x    = (const float*)d_in[0];
    const float* conv = (const float*)d_in[1];
    const float* bias = (const float*)d_in[2];
    float* out = (float*)d_out;
    unsigned short* ws16 = (unsigned short*)d_ws;

    prep<<<dim3((245000 + 10496 + 255) / 256), dim3(256), 0, stream>>>(x, conv, ws16);
    conv4d_mfma<<<dim3(8, 98), dim3(384), 0, stream>>>(ws16, bias, out);
}

// Round 5
// 82.313 us; speedup vs baseline: 1.0408x; 1.0408x over previous
//
#include <hip/hip_runtime.h>

// Conv4D (2,8,7,7,48,48) fp32, 3x3x3x3 pad 1, 8->8 ch — bf16 MFMA implicit GEMM.
// R5: barrier-free main kernel, 2x occupancy, global slot tables, full 1-ahead
//     software pipeline. (R4's LDS staging was ds_read-issue-bound + low occ.)
//
// d_ws layout (re-poisoned each launch; fully rewritten by prep):
//   [0,       3920000)  xp: bf16 x as [b][uv 49][hh 50][ww 50][c 8], h/w halo zeros
//   [3920000, 3940992)  Wp: A-frag weights [tap 82][m 16][j 8] bf16 (tap 81 = 0)
//   [3940992, 4009984)  tbl: per-image slot tables [img 98][slot 88] {taboff, woff}

typedef __attribute__((ext_vector_type(8))) short short8;
typedef __attribute__((ext_vector_type(4))) float f32x4;
typedef __attribute__((ext_vector_type(2))) int   i32x2;

#define CSTRIDE (49 * 2304)
#define WP_OFF  3920000
#define WT_OFF  3940992

__device__ __forceinline__ unsigned short f2bf(float f) {
    union { float f; unsigned u; } v; v.f = f;
    unsigned u = v.u;
    return (unsigned short)((u + 0x7FFF + ((u >> 16) & 1)) >> 16);  // RNE
}

// prep: [0,245000) xp groups; [245000,255496) Wp; [255496,264120) slot tables.
__global__ __launch_bounds__(256)
void prep(const float* __restrict__ x, const float* __restrict__ conv,
          unsigned short* __restrict__ ws16) {
    int g = blockIdx.x * 256 + threadIdx.x;
    if (g < 245000) {
        unsigned short vals[8];
#pragma unroll
        for (int c = 0; c < 8; ++c) vals[c] = 0;
        int b  = g / 122500;
        int r  = g - b * 122500;
        int uv = r / 2500;
        int p  = r - uv * 2500;
        int hh = p / 50, ww = p - hh * 50;
        int h = hh - 1, w = ww - 1;
        if (((unsigned)h < 48u) && ((unsigned)w < 48u)) {
            const float* xb = x + ((size_t)b * 8 * 49 + uv) * 2304 + h * 48 + w;
#pragma unroll
            for (int c = 0; c < 8; ++c) vals[c] = f2bf(xb[(size_t)c * CSTRIDE]);
        }
        *(short8*)(ws16 + (size_t)g * 8) = *(const short8*)vals;
        return;
    }
    g -= 245000;
    if (g < 10496) {                          // Wp[tap 82][m 16][j 8]
        int tap = g >> 7;
        int r   = g & 127;
        int m   = r >> 3, j = r & 7;
        unsigned short v = 0;
        if (tap < 81 && m < 8) v = f2bf(conv[m * 648 + tap * 8 + j]);
        ws16[WP_OFF / 2 + g] = v;
        return;
    }
    g -= 10496;
    if (g < 8624) {                           // tbl[img 98][slot 88]
        int img  = g / 88, slot = g - img * 88;
        int b    = img / 49, uv = img - b * 49;
        int u    = uv / 7,   v  = uv - u * 7;
        int cu = 3 - (u == 0) - (u == 6);
        int cv = 3 - (v == 0) - (v == 6);
        int tab, wof;
        if (slot < cu * cv * 9) {
            int g9  = slot / 9, hw9 = slot - 9 * g9;
            int gi0 = g9 / cv,  gi1 = g9 - cv * gi0;
            int i0 = (u == 0) + gi0, i1 = (v == 0) + gi1;
            int uu = u + i0 - 1,     vv = v + i1 - 1;
            int i2 = hw9 / 3,        i3 = hw9 - 3 * i2;
            tab = (((b * 7 + uu) * 7 + vv) * 2500 + i2 * 50 + i3) * 16;
            wof = ((i0 * 3 + i1) * 9 + hw9) * 256;
        } else {
            tab = 0;                          // safe dummy xp offset
            wof = 81 * 256;                   // zero weights
        }
        i32x2 e; e.x = tab; e.y = wof;
        *(i32x2*)((char*)ws16 + WT_OFF + (size_t)g * 8) = e;
    }
}

// Main: grid (36, 98), 128 threads = 2 independent waves, wave = 2 N-tiles.
// No LDS, no __syncthreads, 1-iteration-deep software pipeline.
__global__ __launch_bounds__(128, 6)
void conv4d_mfma(const unsigned short* __restrict__ ws16,
                 const float* __restrict__ bias,
                 float* __restrict__ out) {
    const int img = blockIdx.y;              // b*49 + uv
    const int b   = img / 49;
    const int uvr = img - b * 49;
    const int u   = uvr / 7;
    const int v   = uvr - u * 7;
    const int cu  = 3 - (u == 0) - (u == 6);
    const int cv  = 3 - (v == 0) - (v == 6);
    const int nchunk = (cu * cv * 9 + 3) >> 2;

    const int lane  = threadIdx.x & 63;
    const int wave  = threadIdx.x >> 6;
    const int n     = lane & 15;             // spatial col within 16-tile
    const int quad  = lane >> 4;             // tap-slot within chunk
    const int sbase = blockIdx.x * 64 + wave * 32;

    int myoff0, myoff1;
    {
        int s0 = sbase + n;
        int h0 = s0 / 48, w0 = s0 - h0 * 48;
        myoff0 = (h0 * 50 + w0) * 16;
        int s1 = sbase + 16 + n;
        int h1 = s1 / 48, w1 = s1 - h1 * 48;
        myoff1 = (h1 * 50 + w1) * 16;
    }

    const char* base0 = (const char*)ws16;
    const char* wpb   = base0 + WP_OFF;
    const i32x2* tbl  = (const i32x2*)(base0 + WT_OFF) + img * 88;
    const int n16     = n * 16;

    // Pipeline prologue: slot tables padded to 88 -> prefetch is branchless.
    i32x2 tw = tbl[quad];
    short8 wf  = *(const short8*)(wpb + tw.y + n16);
    short8 xf0 = *(const short8*)(base0 + tw.x + myoff0);
    short8 xf1 = *(const short8*)(base0 + tw.x + myoff1);

    f32x4 acc0 = (f32x4){0.f, 0.f, 0.f, 0.f};
    f32x4 acc1 = acc0;

    for (int c = 0; c < nchunk; ++c) {
        i32x2 twn = tbl[4 * (c + 1) + quad];           // slot <= 87: in-table
        short8 wfn  = *(const short8*)(wpb + twn.y + n16);
        short8 xf0n = *(const short8*)(base0 + twn.x + myoff0);
        short8 xf1n = *(const short8*)(base0 + twn.x + myoff1);
        acc0 = __builtin_amdgcn_mfma_f32_16x16x32_bf16(wf, xf0, acc0, 0, 0, 0);
        acc1 = __builtin_amdgcn_mfma_f32_16x16x32_bf16(wf, xf1, acc1, 0, 0, 0);
        wf = wfn; xf0 = xf0n; xf1 = xf1n;
    }

    // C/D: row(=o) = quad*4 + reg, col = lane&15. Rows 8..15 unused.
    if (quad < 2) {
        f32x4 bb = *(const f32x4*)(bias + quad * 4);
        float* ob = out + ((size_t)b * 8 * 49 + uvr) * 2304 + sbase + n;
#pragma unroll
        for (int r = 0; r < 4; ++r) {
            int o = quad * 4 + r;
            ob[(size_t)o * CSTRIDE]      = acc0[r] + bb[r];
            ob[(size_t)o * CSTRIDE + 16] = acc1[r] + bb[r];
        }
    }
}

extern "C" void kernel_launch(void* const* d_in, const int* in_sizes, int n_in,
                              void* d_out, int out_size, void* d_ws, size_t ws_size,
                              hipStream_t stream) {
    const float* x    = (const float*)d_in[0];
    const float* conv = (const float*)d_in[1];
    const float* bias = (const float*)d_in[2];
    float* out = (float*)d_out;
    unsigned short* ws16 = (unsigned short*)d_ws;

    prep<<<dim3((245000 + 10496 + 8624 + 255) / 256), dim3(256), 0, stream>>>(x, conv, ws16);
    conv4d_mfma<<<dim3(36, 98), dim3(128), 0, stream>>>(ws16, bias, out);
}

// Round 6
// 78.593 us; speedup vs baseline: 1.0900x; 1.0473x over previous
//
#include <hip/hip_runtime.h>

// Conv4D (2,8,7,7,48,48) fp32, 3x3x3x3 pad 1, 8->8 ch — bf16 MFMA implicit GEMM.
// R6: dependency-free K-loop. Per-wave: hoist all 21 packed slot-table entries
// into registers up-front (one L2 round trip), then 21 fully-unrolled chunk
// bodies whose loads are mutually independent (compiler software-pipelines).
// No LDS, no barriers, 128-thr blocks, <=128 VGPR (16 waves/CU).
//
// d_ws layout (re-poisoned each launch; fully rewritten by prep):
//   [0,       3920000)  xp: bf16 x as [b][uv 49][hh 50][ww 50][c 8], h/w halo zeros
//   [3920000, 3960000)  zero slice (2500 * 16 B) backing invalid slots
//   [3960000, 3981504)  Wp: A-frag weights [tap 84][m 16][j 8] bf16 (taps 81..83 = 0)
//   [3981504, 4016000)  tbl: [img 98][slot 88] i32 = taboff | (wtap << 22)

typedef __attribute__((ext_vector_type(8))) short short8;
typedef __attribute__((ext_vector_type(4))) float f32x4;

#define CSTRIDE (49 * 2304)
#define ZS_OFF  3920000
#define WP_OFF  3960000
#define WT_OFF  3981504

__device__ __forceinline__ unsigned short f2bf(float f) {
    union { float f; unsigned u; } v; v.f = f;
    unsigned u = v.u;
    return (unsigned short)((u + 0x7FFF + ((u >> 16) & 1)) >> 16);  // RNE
}

// prep: [0,245000) xp | [245000,247500) zero slice | +10752 Wp | +8624 tbl
__global__ __launch_bounds__(256)
void prep(const float* __restrict__ x, const float* __restrict__ conv,
          unsigned short* __restrict__ ws16) {
    int g = blockIdx.x * 256 + threadIdx.x;
    if (g < 247500) {
        unsigned short vals[8];
#pragma unroll
        for (int c = 0; c < 8; ++c) vals[c] = 0;
        if (g < 245000) {
            int b  = g / 122500;
            int r  = g - b * 122500;
            int uv = r / 2500;
            int p  = r - uv * 2500;
            int hh = p / 50, ww = p - hh * 50;
            int h = hh - 1, w = ww - 1;
            if (((unsigned)h < 48u) && ((unsigned)w < 48u)) {
                const float* xb = x + ((size_t)b * 8 * 49 + uv) * 2304 + h * 48 + w;
#pragma unroll
                for (int c = 0; c < 8; ++c) vals[c] = f2bf(xb[(size_t)c * CSTRIDE]);
            }
        }
        *(short8*)(ws16 + (size_t)g * 8) = *(const short8*)vals;   // includes zero slice
        return;
    }
    g -= 247500;
    if (g < 10752) {                          // Wp[tap 84][m 16][j 8]
        int tap = g >> 7;
        int r   = g & 127;
        int m   = r >> 3, j = r & 7;
        unsigned short v = 0;
        if (tap < 81 && m < 8) v = f2bf(conv[m * 648 + tap * 8 + j]);
        ws16[WP_OFF / 2 + g] = v;
        return;
    }
    g -= 10752;
    if (g < 8624) {                           // tbl[img 98][slot 88], packed i32
        int img  = g / 88, slot = g - img * 88;
        int b    = img / 49, uv = img - b * 49;
        int u    = uv / 7,   v  = uv - u * 7;
        int cu = 3 - (u == 0) - (u == 6);
        int cv = 3 - (v == 0) - (v == 6);
        int entry;
        if (slot < cu * cv * 9) {
            int g9  = slot / 9, hw9 = slot - 9 * g9;
            int gi0 = g9 / cv,  gi1 = g9 - cv * gi0;
            int i0 = (u == 0) + gi0, i1 = (v == 0) + gi1;
            int uu = u + i0 - 1,     vv = v + i1 - 1;
            int i2 = hw9 / 3,        i3 = hw9 - 3 * i2;
            int tab  = (((b * 7 + uu) * 7 + vv) * 2500 + i2 * 50 + i3) * 16;
            int wtap = (i0 * 3 + i1) * 9 + hw9;
            entry = tab | (wtap << 22);
        } else {
            entry = ZS_OFF | (81 << 22);      // zero data x zero weights
        }
        ((int*)((char*)ws16 + WT_OFF))[g] = entry;
    }
}

// Main: grid (36, 98), 128 threads = 2 independent waves, wave = 2 N-tiles.
__global__ __launch_bounds__(128, 4)
void conv4d_mfma(const unsigned short* __restrict__ ws16,
                 const float* __restrict__ bias,
                 float* __restrict__ out) {
    const int img = blockIdx.y;              // b*49 + uv
    const int b   = img / 49;
    const int uvr = img - b * 49;
    const int u   = uvr / 7;
    const int v   = uvr - u * 7;
    const int cu  = 3 - (u == 0) - (u == 6);
    const int cv  = 3 - (v == 0) - (v == 6);
    const int nchunk = (cu * cv * 9 + 3) >> 2;   // 9, 14, or 21

    const int lane  = threadIdx.x & 63;
    const int wave  = threadIdx.x >> 6;
    const int n     = lane & 15;             // spatial col within 16-tile
    const int quad  = lane >> 4;             // tap-slot within chunk
    const int sbase = blockIdx.x * 64 + wave * 32;

    int myoff0, myoff1;
    {
        int s0 = sbase + n;
        int h0 = s0 / 48, w0 = s0 - h0 * 48;
        myoff0 = (h0 * 50 + w0) * 16;
        int s1 = sbase + 16 + n;
        int h1 = s1 / 48, w1 = s1 - h1 * 48;
        myoff1 = (h1 * 50 + w1) * 16;
    }

    const char* base0 = (const char*)ws16;
    const char* wpb   = base0 + WP_OFF;
    const int*  tblp  = (const int*)(base0 + WT_OFF) + img * 88;
    const int   n16   = n * 16;

    // Hoist ALL table entries for this wave's quad into registers: 21
    // independent 4 B loads (slots 4c+quad <= 83 < 88 always in-table).
    int t[21];
#pragma unroll
    for (int c = 0; c < 21; ++c) t[c] = tblp[4 * c + quad];

    f32x4 acc0 = (f32x4){0.f, 0.f, 0.f, 0.f};
    f32x4 acc1 = acc0;

#define CHUNK(c)                                                              \
    {                                                                         \
        int e   = t[c];                                                       \
        int tab = e & 0x3FFFFF;                                               \
        int wof = (e >> 22) << 8;                                             \
        short8 wf  = *(const short8*)(wpb + wof + n16);                       \
        short8 xf0 = *(const short8*)(base0 + tab + myoff0);                  \
        short8 xf1 = *(const short8*)(base0 + tab + myoff1);                  \
        acc0 = __builtin_amdgcn_mfma_f32_16x16x32_bf16(wf, xf0, acc0, 0, 0, 0); \
        acc1 = __builtin_amdgcn_mfma_f32_16x16x32_bf16(wf, xf1, acc1, 0, 0, 0); \
    }

    // Uniform sections matching nchunk in {9, 14, 21}; bodies fully unrolled,
    // loads within a section are mutually independent -> deep pipelining.
#pragma unroll
    for (int c = 0; c < 9; ++c) CHUNK(c);
    if (nchunk > 9) {
#pragma unroll
        for (int c = 9; c < 14; ++c) CHUNK(c);
        if (nchunk > 14) {
#pragma unroll
            for (int c = 14; c < 21; ++c) CHUNK(c);
        }
    }
#undef CHUNK

    // C/D: row(=o) = quad*4 + reg, col = lane&15. Rows 8..15 unused.
    if (quad < 2) {
        f32x4 bb = *(const f32x4*)(bias + quad * 4);
        float* ob = out + ((size_t)b * 8 * 49 + uvr) * 2304 + sbase + n;
#pragma unroll
        for (int r = 0; r < 4; ++r) {
            int o = quad * 4 + r;
            ob[(size_t)o * CSTRIDE]      = acc0[r] + bb[r];
            ob[(size_t)o * CSTRIDE + 16] = acc1[r] + bb[r];
        }
    }
}

extern "C" void kernel_launch(void* const* d_in, const int* in_sizes, int n_in,
                              void* d_out, int out_size, void* d_ws, size_t ws_size,
                              hipStream_t stream) {
    const float* x    = (const float*)d_in[0];
    const float* conv = (const float*)d_in[1];
    const float* bias = (const float*)d_in[2];
    float* out = (float*)d_out;
    unsigned short* ws16 = (unsigned short*)d_ws;

    prep<<<dim3((247500 + 10752 + 8624 + 255) / 256), dim3(256), 0, stream>>>(x, conv, ws16);
    conv4d_mfma<<<dim3(36, 98), dim3(128), 0, stream>>>(ws16, bias, out);
}

// Round 7
// 76.728 us; speedup vs baseline: 1.1165x; 1.0243x over previous
//
#include <hip/hip_runtime.h>

// Conv4D (2,8,7,7,48,48) fp32, 3x3x3x3 pad 1, 8->8 ch — bf16 MFMA implicit GEMM.
// R7: 4 N-tiles per wave (A-fragment traffic halved vs R6), register-hoisted
// packed slot tables, fully-unrolled 9/14/21 chunk sections, no LDS/barriers.
//
// d_ws layout (re-poisoned each launch; fully rewritten by prep):
//   [0,       3920000)  xp: bf16 x as [b][uv 49][hh 50][ww 50][c 8], h/w halo zeros
//   [3920000, 3960000)  zero slice (2500 * 16 B) backing invalid slots
//   [3960000, 3981504)  Wp: A-frag weights [tap 84][m 16][j 8] bf16 (taps 81..83 = 0)
//   [3981504, 4016000)  tbl: [img 98][slot 88] i32 = taboff | (wtap << 22)

typedef __attribute__((ext_vector_type(8))) short short8;
typedef __attribute__((ext_vector_type(4))) float f32x4;

#define CSTRIDE (49 * 2304)
#define ZS_OFF  3920000
#define WP_OFF  3960000
#define WT_OFF  3981504

__device__ __forceinline__ unsigned short f2bf(float f) {
    union { float f; unsigned u; } v; v.f = f;
    unsigned u = v.u;
    return (unsigned short)((u + 0x7FFF + ((u >> 16) & 1)) >> 16);  // RNE
}

// prep: [0,245000) xp | [245000,247500) zero slice | +10752 Wp | +8624 tbl
__global__ __launch_bounds__(256)
void prep(const float* __restrict__ x, const float* __restrict__ conv,
          unsigned short* __restrict__ ws16) {
    int g = blockIdx.x * 256 + threadIdx.x;
    if (g < 247500) {
        unsigned short vals[8];
#pragma unroll
        for (int c = 0; c < 8; ++c) vals[c] = 0;
        if (g < 245000) {
            int b  = g / 122500;
            int r  = g - b * 122500;
            int uv = r / 2500;
            int p  = r - uv * 2500;
            int hh = p / 50, ww = p - hh * 50;
            int h = hh - 1, w = ww - 1;
            if (((unsigned)h < 48u) && ((unsigned)w < 48u)) {
                const float* xb = x + ((size_t)b * 8 * 49 + uv) * 2304 + h * 48 + w;
#pragma unroll
                for (int c = 0; c < 8; ++c) vals[c] = f2bf(xb[(size_t)c * CSTRIDE]);
            }
        }
        *(short8*)(ws16 + (size_t)g * 8) = *(const short8*)vals;   // includes zero slice
        return;
    }
    g -= 247500;
    if (g < 10752) {                          // Wp[tap 84][m 16][j 8]
        int tap = g >> 7;
        int r   = g & 127;
        int m   = r >> 3, j = r & 7;
        unsigned short v = 0;
        if (tap < 81 && m < 8) v = f2bf(conv[m * 648 + tap * 8 + j]);
        ws16[WP_OFF / 2 + g] = v;
        return;
    }
    g -= 10752;
    if (g < 8624) {                           // tbl[img 98][slot 88], packed i32
        int img  = g / 88, slot = g - img * 88;
        int b    = img / 49, uv = img - b * 49;
        int u    = uv / 7,   v  = uv - u * 7;
        int cu = 3 - (u == 0) - (u == 6);
        int cv = 3 - (v == 0) - (v == 6);
        int entry;
        if (slot < cu * cv * 9) {
            int g9  = slot / 9, hw9 = slot - 9 * g9;
            int gi0 = g9 / cv,  gi1 = g9 - cv * gi0;
            int i0 = (u == 0) + gi0, i1 = (v == 0) + gi1;
            int uu = u + i0 - 1,     vv = v + i1 - 1;
            int i2 = hw9 / 3,        i3 = hw9 - 3 * i2;
            int tab  = (((b * 7 + uu) * 7 + vv) * 2500 + i2 * 50 + i3) * 16;
            int wtap = (i0 * 3 + i1) * 9 + hw9;
            entry = tab | (wtap << 22);
        } else {
            entry = ZS_OFF | (81 << 22);      // zero data x zero weights
        }
        ((int*)((char*)ws16 + WT_OFF))[g] = entry;
    }
}

// Main: grid (18, 98), 128 threads = 2 independent waves, wave = 4 N-tiles.
__global__ __launch_bounds__(128, 4)
void conv4d_mfma(const unsigned short* __restrict__ ws16,
                 const float* __restrict__ bias,
                 float* __restrict__ out) {
    const int img = blockIdx.y;              // b*49 + uv
    const int b   = img / 49;
    const int uvr = img - b * 49;
    const int u   = uvr / 7;
    const int v   = uvr - u * 7;
    const int cu  = 3 - (u == 0) - (u == 6);
    const int cv  = 3 - (v == 0) - (v == 6);
    const int nchunk = (cu * cv * 9 + 3) >> 2;   // 9, 14, or 21

    const int lane  = threadIdx.x & 63;
    const int wave  = threadIdx.x >> 6;
    const int n     = lane & 15;             // spatial col within 16-tile
    const int quad  = lane >> 4;             // tap-slot within chunk
    const int sbase = blockIdx.x * 128 + wave * 64;

    int myoff[4];
#pragma unroll
    for (int t = 0; t < 4; ++t) {
        int s = sbase + t * 16 + n;          // 16-aligned tiles never cross h rows
        int h = s / 48, w = s - h * 48;
        myoff[t] = (h * 50 + w) * 16;
    }

    const char* base0 = (const char*)ws16;
    const char* wpb   = base0 + WP_OFF;
    const int*  tblp  = (const int*)(base0 + WT_OFF) + img * 88;
    const int   n16   = n * 16;

    // Hoist ALL table entries for this wave's quad into registers: 21
    // independent 4 B loads (slots 4c+quad <= 83 < 88 always in-table).
    int t[21];
#pragma unroll
    for (int c = 0; c < 21; ++c) t[c] = tblp[4 * c + quad];

    f32x4 acc0 = (f32x4){0.f, 0.f, 0.f, 0.f};
    f32x4 acc1 = acc0, acc2 = acc0, acc3 = acc0;

#define CHUNK(c)                                                              \
    {                                                                         \
        int e   = t[c];                                                       \
        int tab = e & 0x3FFFFF;                                               \
        int wof = (e >> 22) << 8;                                             \
        short8 wf  = *(const short8*)(wpb + wof + n16);                       \
        const char* xb = base0 + tab;                                         \
        short8 xf0 = *(const short8*)(xb + myoff[0]);                         \
        short8 xf1 = *(const short8*)(xb + myoff[1]);                         \
        short8 xf2 = *(const short8*)(xb + myoff[2]);                         \
        short8 xf3 = *(const short8*)(xb + myoff[3]);                         \
        acc0 = __builtin_amdgcn_mfma_f32_16x16x32_bf16(wf, xf0, acc0, 0, 0, 0); \
        acc1 = __builtin_amdgcn_mfma_f32_16x16x32_bf16(wf, xf1, acc1, 0, 0, 0); \
        acc2 = __builtin_amdgcn_mfma_f32_16x16x32_bf16(wf, xf2, acc2, 0, 0, 0); \
        acc3 = __builtin_amdgcn_mfma_f32_16x16x32_bf16(wf, xf3, acc3, 0, 0, 0); \
    }

    // Uniform sections matching nchunk in {9, 14, 21}; bodies fully unrolled,
    // loads within a section are mutually independent -> deep pipelining.
#pragma unroll
    for (int c = 0; c < 9; ++c) CHUNK(c);
    if (nchunk > 9) {
#pragma unroll
        for (int c = 9; c < 14; ++c) CHUNK(c);
        if (nchunk > 14) {
#pragma unroll
            for (int c = 14; c < 21; ++c) CHUNK(c);
        }
    }
#undef CHUNK

    // C/D: row(=o) = quad*4 + reg, col = lane&15. Rows 8..15 unused.
    if (quad < 2) {
        f32x4 bb = *(const f32x4*)(bias + quad * 4);
        float* ob = out + ((size_t)b * 8 * 49 + uvr) * 2304 + sbase + n;
        f32x4 av[4] = {acc0, acc1, acc2, acc3};
#pragma unroll
        for (int tt = 0; tt < 4; ++tt) {
#pragma unroll
            for (int r = 0; r < 4; ++r) {
                int o = quad * 4 + r;
                ob[(size_t)o * CSTRIDE + tt * 16] = av[tt][r] + bb[r];
            }
        }
    }
}

extern "C" void kernel_launch(void* const* d_in, const int* in_sizes, int n_in,
                              void* d_out, int out_size, void* d_ws, size_t ws_size,
                              hipStream_t stream) {
    const float* x    = (const float*)d_in[0];
    const float* conv = (const float*)d_in[1];
    const float* bias = (const float*)d_in[2];
    float* out = (float*)d_out;
    unsigned short* ws16 = (unsigned short*)d_ws;

    prep<<<dim3((247500 + 10752 + 8624 + 255) / 256), dim3(256), 0, stream>>>(x, conv, ws16);
    conv4d_mfma<<<dim3(18, 98), dim3(128), 0, stream>>>(ws16, bias, out);
}

// Round 9
// 74.877 us; speedup vs baseline: 1.1441x; 1.0247x over previous
//
#include <hip/hip_runtime.h>

// Conv4D (2,8,7,7,48,48) fp32, 3x3x3x3 pad 1, 8->8 ch — bf16 MFMA implicit GEMM.
// R8b: full-M packing (compile fix: no constexpr in CHUNK). C rows m = o + 8d
// encode (out-ch o, out-row h+d); B taps j2 = i2+d span quad=0..3, so K per
// (u,v)-slice = 4x3x8 = 96 = exactly 3 chunks of 16x16x32 — no padded tail,
// all 16 M rows used. vs R7: MFMA x0.64, fragment traffic x0.63.
// Register-hoisted 9-entry uniform slice table, fully-unrolled 12/+6/+9
// chunk sections, no LDS, no barriers.
//
// d_ws layout (re-poisoned each launch; fully rewritten by prep):
//   [0,       3920000)  xp: bf16 x as [b][uv 49][hh 50][ww 50][c 8], halo zeros
//   [3920000, 3960000)  zero slice (40 KB) backing invalid (u,v) slices
//   [3960000, 3987648)  Wp2: A-frags [aslot 27 = i0i1*3+i3][lane 64][j 8] bf16
//                       Wp2[as][lane][j] = W[o=m&7, i0i1, i2=q-d, i3, c=j],
//                       m=lane&15, q=lane>>4, d=m>>3; zero if q-d not in 0..2
//   [3987648, 3991176)  tbl: [img 98][k 9] i32 = uvbase | (i0i1 << 22)

typedef __attribute__((ext_vector_type(8))) short short8;
typedef __attribute__((ext_vector_type(4))) float f32x4;

#define CSTRIDE (49 * 2304)
#define ZS_OFF  3920000
#define WP_OFF  3960000
#define WT_OFF  3987648

__device__ __forceinline__ unsigned short f2bf(float f) {
    union { float f; unsigned u; } v; v.f = f;
    unsigned u = v.u;
    return (unsigned short)((u + 0x7FFF + ((u >> 16) & 1)) >> 16);  // RNE
}

// prep: [0,247500) xp+zero | +13824 Wp2 | +882 tbl   (262206 threads)
__global__ __launch_bounds__(256)
void prep(const float* __restrict__ x, const float* __restrict__ conv,
          unsigned short* __restrict__ ws16) {
    int g = blockIdx.x * 256 + threadIdx.x;
    if (g < 247500) {
        unsigned short vals[8];
#pragma unroll
        for (int c = 0; c < 8; ++c) vals[c] = 0;
        if (g < 245000) {
            int b  = g / 122500;
            int r  = g - b * 122500;
            int uv = r / 2500;
            int p  = r - uv * 2500;
            int hh = p / 50, ww = p - hh * 50;
            int h = hh - 1, w = ww - 1;
            if (((unsigned)h < 48u) && ((unsigned)w < 48u)) {
                const float* xb = x + ((size_t)b * 8 * 49 + uv) * 2304 + h * 48 + w;
#pragma unroll
                for (int c = 0; c < 8; ++c) vals[c] = f2bf(xb[(size_t)c * CSTRIDE]);
            }
        }
        *(short8*)(ws16 + (size_t)g * 8) = *(const short8*)vals;   // incl. zero slice
        return;
    }
    g -= 247500;
    if (g < 13824) {                          // Wp2: 27 aslots * 512 elems
        int as   = g >> 9;
        int r    = g & 511;
        int lane = r >> 3, j = r & 7;
        int m = lane & 15, q = lane >> 4;
        int o = m & 7, d = m >> 3;
        int i0i1 = as / 3, i3 = as - 3 * i0i1;
        int i2 = q - d;
        unsigned short v = 0;
        if ((unsigned)i2 < 3u)
            v = f2bf(conv[o * 648 + ((i0i1 * 3 + i2) * 3 + i3) * 8 + j]);
        ws16[WP_OFF / 2 + g] = v;
        return;
    }
    g -= 13824;
    if (g < 882) {                            // tbl[img 98][k 9]
        int img = g / 9, k = g - img * 9;
        int b   = img / 49, uv = img - b * 49;
        int u   = uv / 7,   v  = uv - u * 7;
        int entry = ZS_OFF;                   // default: zero slice, i0i1=0
        int cnt = 0;
        for (int i01 = 0; i01 < 9; ++i01) {
            int i0 = i01 / 3, i1 = i01 - 3 * i0;
            int uu = u + i0 - 1, vv = v + i1 - 1;
            if (((unsigned)uu < 7u) && ((unsigned)vv < 7u)) {
                if (cnt == k)
                    entry = (((b * 7 + uu) * 7 + vv) * 40000) | (i01 << 22);
                ++cnt;
            }
        }
        ((int*)((char*)ws16 + WT_OFF))[g] = entry;
    }
}

// Main: grid (18, 98), 128 thr = 2 waves; wave = 2 dtiles (2 rows x 16 cols each).
__global__ __launch_bounds__(128, 4)
void conv4d_mfma(const unsigned short* __restrict__ ws16,
                 const float* __restrict__ bias,
                 float* __restrict__ out) {
    const int img = blockIdx.y;              // b*49 + uv
    const int b   = img / 49;
    const int uvr = img - b * 49;
    const int u   = uvr / 7;
    const int v   = uvr - u * 7;
    const int cu  = 3 - (u == 0) - (u == 6);
    const int cv  = 3 - (v == 0) - (v == 6);
    const int nchunk = cu * cv * 3;          // 12, 18, or 27 (exact, no tail)

    const int lane = threadIdx.x & 63;
    const int wave = threadIdx.x >> 6;
    const int n    = lane & 15;              // col within 16-tile (B col, A m-row)
    const int quad = lane >> 4;              // j2 tap-row (B), k-group (A)

    // Wave's two dtiles: dt = widx*2 + {0,1}; dt -> (row-pair rp, col base w0).
    const int widx = blockIdx.x * 2 + wave;  // 0..35
    const int dt0  = widx * 2;
    const int rp0  = dt0 / 3,        w00 = (dt0 - 3 * rp0) * 16;
    const int dt1  = dt0 + 1;
    const int rp1  = dt1 / 3,        w01 = (dt1 - 3 * rp1) * 16;

    // B per-lane offsets: row' = rp*2 + quad, col' = w0 + n (+ i3*16 via tab).
    const int myoff0 = ((rp0 * 2 + quad) * 50 + w00 + n) * 16;
    const int myoff1 = ((rp1 * 2 + quad) * 50 + w01 + n) * 16;

    const char* base0  = (const char*)ws16;
    const char* wpb    = base0 + WP_OFF;
    const int   lane16 = lane * 16;

    // Hoist the 9 uniform slice-table entries into registers.
    const int* tblp = (const int*)(base0 + WT_OFF) + img * 9;
    int t[9];
#pragma unroll
    for (int k = 0; k < 9; ++k) t[k] = tblp[k];

    f32x4 acc0 = (f32x4){0.f, 0.f, 0.f, 0.f};
    f32x4 acc1 = acc0;

#define CHUNK(c)                                                               \
    {                                                                          \
        int sl = (c) / 3, i3 = (c) % 3;                                        \
        int e   = t[sl];                                                       \
        int tab = (e & 0x3FFFFF) + i3 * 16;                                    \
        int wof = (((e >> 22) * 3 + i3) << 10);                                \
        short8 wf  = *(const short8*)(wpb + wof + lane16);                     \
        const char* xb = base0 + tab;                                          \
        short8 xf0 = *(const short8*)(xb + myoff0);                            \
        short8 xf1 = *(const short8*)(xb + myoff1);                            \
        acc0 = __builtin_amdgcn_mfma_f32_16x16x32_bf16(wf, xf0, acc0, 0, 0, 0);\
        acc1 = __builtin_amdgcn_mfma_f32_16x16x32_bf16(wf, xf1, acc1, 0, 0, 0);\
    }

    // Exact sections for nchunk in {12, 18, 27}.
#pragma unroll
    for (int c = 0; c < 12; ++c) CHUNK(c);
    if (nchunk > 12) {
#pragma unroll
        for (int c = 12; c < 18; ++c) CHUNK(c);
        if (nchunk > 18) {
#pragma unroll
            for (int c = 18; c < 27; ++c) CHUNK(c);
        }
    }
#undef CHUNK

    // C/D: row m = quad*4 + r = o + 8d -> o = (quad&1)*4 + r, d = quad>>1.
    // col = n. Out row = rp*2 + d, out col = w0 + n.
    {
        const int d  = quad >> 1;
        const int oq = (quad & 1) * 4;
        const f32x4 bb = *(const f32x4*)(bias + oq);
        float* obase = out + ((size_t)(b * 8 + oq) * 49 + uvr) * 2304;
        float* ob0 = obase + (rp0 * 2 + d) * 48 + w00 + n;
        float* ob1 = obase + (rp1 * 2 + d) * 48 + w01 + n;
#pragma unroll
        for (int r = 0; r < 4; ++r) {
            ob0[(size_t)r * CSTRIDE] = acc0[r] + bb[r];
            ob1[(size_t)r * CSTRIDE] = acc1[r] + bb[r];
        }
    }
}

extern "C" void kernel_launch(void* const* d_in, const int* in_sizes, int n_in,
                              void* d_out, int out_size, void* d_ws, size_t ws_size,
                              hipStream_t stream) {
    const float* x    = (const float*)d_in[0];
    const float* conv = (const float*)d_in[1];
    const float* bias = (const float*)d_in[2];
    float* out = (float*)d_out;
    unsigned short* ws16 = (unsigned short*)d_ws;

    prep<<<dim3((247500 + 13824 + 882 + 255) / 256), dim3(256), 0, stream>>>(x, conv, ws16);
    conv4d_mfma<<<dim3(18, 98), dim3(128), 0, stream>>>(ws16, bias, out);
}